// Round 2
// baseline (589.540 us; speedup 1.0000x reference)
//
#include <hip/hip_runtime.h>
#include <cstdint>
#include <cstddef>

#define N_NODES 100000
#define N_EDGES 3200000
#define F_IN 128
#define F_OUT 128

// first index i in [0,n) with a[i] >= key (a ascending)
__device__ __forceinline__ int lower_bound_i32(const int* __restrict__ a, int n, int key) {
    int lo = 0, hi = n;
    while (lo < hi) {
        int mid = (lo + hi) >> 1;
        if (a[mid] < key) lo = mid + 1; else hi = mid;
    }
    return lo;
}

// out[row,:] = sum_{e in row's segment} vals[e] * x[cols[e],:]
// One 64-lane wave per node row; each lane owns a float2 (8B) slice of the 128 features.
__global__ __launch_bounds__(256) void spmm_ax_kernel(
    const float* __restrict__ x,
    const int*   __restrict__ rows,
    const int*   __restrict__ cols,
    const float* __restrict__ vals,
    float*       __restrict__ out)
{
    const int row  = blockIdx.x * 4 + (threadIdx.x >> 6);
    const int lane = threadIdx.x & 63;
    if (row >= N_NODES) return;

    // adj_rows is sorted: binary-search the segment (uniform across the wave -> broadcast loads)
    const int e0 = lower_bound_i32(rows, N_EDGES, row);
    const int e1 = lower_bound_i32(rows, N_EDGES, row + 1);

    const float2* __restrict__ x2 = reinterpret_cast<const float2*>(x);
    float2 acc; acc.x = 0.f; acc.y = 0.f;

    int e = e0;
    // 2-edge unroll: two independent gathers in flight
    for (; e + 2 <= e1; e += 2) {
        const int   c0 = cols[e],     c1 = cols[e + 1];
        const float v0 = vals[e],     v1 = vals[e + 1];
        const float2 a0 = x2[(size_t)c0 * 64 + lane];
        const float2 a1 = x2[(size_t)c1 * 64 + lane];
        acc.x = fmaf(v0, a0.x, acc.x);
        acc.y = fmaf(v0, a0.y, acc.y);
        acc.x = fmaf(v1, a1.x, acc.x);
        acc.y = fmaf(v1, a1.y, acc.y);
    }
    if (e < e1) {
        const int   c = cols[e];
        const float v = vals[e];
        const float2 a = x2[(size_t)c * 64 + lane];
        acc.x = fmaf(v, a.x, acc.x);
        acc.y = fmaf(v, a.y, acc.y);
    }
    reinterpret_cast<float2*>(out)[(size_t)row * 64 + lane] = acc;
}

// In-place: out[r,:] = relu(out[r,:] @ W + b).  Safe because each block stages its
// 64 rows into LDS (barrier) before overwriting them, and blocks own disjoint rows.
__global__ __launch_bounds__(256) void gemm_bias_relu_inplace(
    float*       __restrict__ out,
    const float* __restrict__ W,
    const float* __restrict__ bias)
{
    __shared__ float Ws[F_IN][F_OUT];   // 64 KB
    __shared__ float As[64][F_IN];      // 32 KB
    const int t  = threadIdx.x;
    const int r0 = blockIdx.x * 64;
    const int rows_here = (N_NODES - r0 < 64) ? (N_NODES - r0) : 64;

    {
        const float4* __restrict__ W4 = reinterpret_cast<const float4*>(W);
        float4* Ws4 = reinterpret_cast<float4*>(&Ws[0][0]);
        #pragma unroll
        for (int i = 0; i < (F_IN * F_OUT / 4) / 256; ++i)   // 16 iters
            Ws4[t + i * 256] = W4[t + i * 256];

        const float4* __restrict__ A4 =
            reinterpret_cast<const float4*>(out + (size_t)r0 * F_IN);
        float4* As4 = reinterpret_cast<float4*>(&As[0][0]);
        const int nA = rows_here * (F_IN / 4);
        for (int i = t; i < nA; i += 256) As4[i] = A4[i];
    }
    __syncthreads();

    const int tr = t >> 5;   // 0..7  -> rows tr*8 .. tr*8+7
    const int tc = t & 31;   // 0..31 -> cols tc*4 .. tc*4+3
    float acc[8][4];
    #pragma unroll
    for (int rr = 0; rr < 8; ++rr)
        #pragma unroll
        for (int cc = 0; cc < 4; ++cc) acc[rr][cc] = 0.f;

    for (int k = 0; k < F_IN; ++k) {
        const float4 w = *reinterpret_cast<const float4*>(&Ws[k][tc * 4]);
        float a[8];
        #pragma unroll
        for (int rr = 0; rr < 8; ++rr) a[rr] = As[tr * 8 + rr][k];  // broadcast reads
        #pragma unroll
        for (int rr = 0; rr < 8; ++rr) {
            acc[rr][0] = fmaf(a[rr], w.x, acc[rr][0]);
            acc[rr][1] = fmaf(a[rr], w.y, acc[rr][1]);
            acc[rr][2] = fmaf(a[rr], w.z, acc[rr][2]);
            acc[rr][3] = fmaf(a[rr], w.w, acc[rr][3]);
        }
    }

    const float4 bb = *reinterpret_cast<const float4*>(&bias[tc * 4]);
    #pragma unroll
    for (int rr = 0; rr < 8; ++rr) {
        const int r = r0 + tr * 8 + rr;
        if (r < N_NODES) {
            float4 o;
            o.x = fmaxf(acc[rr][0] + bb.x, 0.f);
            o.y = fmaxf(acc[rr][1] + bb.y, 0.f);
            o.z = fmaxf(acc[rr][2] + bb.z, 0.f);
            o.w = fmaxf(acc[rr][3] + bb.w, 0.f);
            *reinterpret_cast<float4*>(&out[(size_t)r * F_OUT + tc * 4]) = o;
        }
    }
}

extern "C" void kernel_launch(void* const* d_in, const int* in_sizes, int n_in,
                              void* d_out, int out_size, void* d_ws, size_t ws_size,
                              hipStream_t stream) {
    const float* x    = (const float*)d_in[0];
    const int*   rows = (const int*)  d_in[1];
    const int*   cols = (const int*)  d_in[2];
    const float* vals = (const float*)d_in[3];
    const float* W    = (const float*)d_in[4];
    const float* b    = (const float*)d_in[5];
    float* out = (float*)d_out;

    // Step 1: out = A @ x   (writes every row, including empty segments -> 0)
    spmm_ax_kernel<<<(N_NODES + 3) / 4, 256, 0, stream>>>(x, rows, cols, vals, out);
    // Step 2: out = relu(out @ W + b), in-place
    gemm_bias_relu_inplace<<<(N_NODES + 63) / 64, 256, 0, stream>>>(out, W, b);
}

// Round 3
// 394.969 us; speedup vs baseline: 1.4926x; 1.4926x over previous
//
#include <hip/hip_runtime.h>
#include <cstdint>
#include <cstddef>

#define N_NODES 100000
#define N_EDGES 3200000
#define F_IN 128
#define F_OUT 128

// first index i in [0,n) with a[i] >= key (a ascending)
__device__ __forceinline__ int lower_bound_i32(const int* __restrict__ a, int n, int key) {
    int lo = 0, hi = n;
    while (lo < hi) {
        int mid = (lo + hi) >> 1;
        if (a[mid] < key) lo = mid + 1; else hi = mid;
    }
    return lo;
}

// rowptr[n] = first edge index with rows[e] >= n, n in [0, N_NODES]
__global__ __launch_bounds__(256) void build_rowptr_kernel(
    const int* __restrict__ rows, int* __restrict__ rowptr)
{
    const int n = blockIdx.x * 256 + threadIdx.x;
    if (n <= N_NODES) rowptr[n] = lower_bound_i32(rows, N_EDGES, n);
}

// out[row,:] = sum_e vals[e] * x[cols[e],:]  — one wave per row, lane owns float2.
// 8-deep gather unroll for memory-level parallelism (latency-bound otherwise).
template<bool USE_ROWPTR>
__global__ __launch_bounds__(256) void spmm_ax_kernel(
    const float* __restrict__ x,
    const int*   __restrict__ rows,
    const int*   __restrict__ cols,
    const float* __restrict__ vals,
    const int*   __restrict__ rowptr,
    float*       __restrict__ out)
{
    const int row  = blockIdx.x * 4 + (threadIdx.x >> 6);
    const int lane = threadIdx.x & 63;
    if (row >= N_NODES) return;

    int e0, e1;
    if (USE_ROWPTR) {
        e0 = rowptr[row];
        e1 = rowptr[row + 1];
    } else {
        e0 = lower_bound_i32(rows, N_EDGES, row);
        e1 = lower_bound_i32(rows, N_EDGES, row + 1);
    }

    const float2* __restrict__ x2 = reinterpret_cast<const float2*>(x);
    float ax = 0.f, ay = 0.f;

    int e = e0;
    for (; e + 8 <= e1; e += 8) {
        int c[8]; float v[8]; float2 a[8];
        #pragma unroll
        for (int j = 0; j < 8; ++j) { c[j] = cols[e + j]; v[j] = vals[e + j]; }
        #pragma unroll
        for (int j = 0; j < 8; ++j) a[j] = x2[(unsigned)c[j] * 64u + lane];
        #pragma unroll
        for (int j = 0; j < 8; ++j) {
            ax = fmaf(v[j], a[j].x, ax);
            ay = fmaf(v[j], a[j].y, ay);
        }
    }
    for (; e + 2 <= e1; e += 2) {
        const int   c0 = cols[e],  c1 = cols[e + 1];
        const float v0 = vals[e],  v1 = vals[e + 1];
        const float2 a0 = x2[(unsigned)c0 * 64u + lane];
        const float2 a1 = x2[(unsigned)c1 * 64u + lane];
        ax = fmaf(v0, a0.x, ax); ay = fmaf(v0, a0.y, ay);
        ax = fmaf(v1, a1.x, ax); ay = fmaf(v1, a1.y, ay);
    }
    if (e < e1) {
        const int   c = cols[e];
        const float v = vals[e];
        const float2 a = x2[(unsigned)c * 64u + lane];
        ax = fmaf(v, a.x, ax); ay = fmaf(v, a.y, ay);
    }

    float2 o; o.x = ax; o.y = ay;
    reinterpret_cast<float2*>(out)[(size_t)row * 64 + lane] = o;
}

// In-place out[r,:] = relu(out[r,:] @ W + b).
// Block owns 64 FULL-WIDTH rows (in-place safe: stages its rows before writing;
// no other block touches them). Two col-half phases keep LDS at 66.5 KB -> 2 blocks/CU.
// All LDS reads are float4; As padded to 132 floats/row (2-way conflicts only = free).
__global__ __launch_bounds__(256) void gemm_bias_relu_inplace(
    float*       __restrict__ out,
    const float* __restrict__ W,
    const float* __restrict__ bias)
{
    __shared__ float As[64][132];    // 33.8 KB  (132*4 = 528 B row stride, 16B-aligned)
    __shared__ float Ws[128][64];    // 32 KB    (one col-half of W)

    const int t  = threadIdx.x;
    const int r0 = blockIdx.x * 64;
    const int rows_here = (N_NODES - r0 < 64) ? (N_NODES - r0) : 64;
    const int ty = t >> 4;           // 0..15 -> rows ty*4..ty*4+3
    const int tx = t & 15;           // 0..15 -> cols tx*4..tx*4+3 (within half)

    // Stage this block's A rows (float4, coalesced 256B runs per row)
    {
        const float4* __restrict__ A4 =
            reinterpret_cast<const float4*>(out + (size_t)r0 * F_IN);
        const int nA = rows_here * 32;            // 32 float4 per row
        for (int i = t; i < nA; i += 256) {
            const int r = i >> 5, kq = i & 31;
            const float4 vA = A4[i];
            *reinterpret_cast<float4*>(&As[r][kq * 4]) = vA;
        }
    }

    const float4* __restrict__ W4 = reinterpret_cast<const float4*>(W);

    for (int h = 0; h < 2; ++h) {
        __syncthreads();   // h=0: A staged; h=1: everyone done reading Ws half 0
        // Stage W[:, h*64 : h*64+64]
        #pragma unroll
        for (int i = 0; i < 8; ++i) {
            const int idx = t + i * 256;          // 0..2047
            const int k = idx >> 4, cq = idx & 15;
            const float4 vW = W4[k * 32 + h * 16 + cq];
            *reinterpret_cast<float4*>(&Ws[k][cq * 4]) = vW;
        }
        __syncthreads();

        float acc[4][4];
        #pragma unroll
        for (int rr = 0; rr < 4; ++rr)
            #pragma unroll
            for (int cc = 0; cc < 4; ++cc) acc[rr][cc] = 0.f;

        #pragma unroll 2
        for (int k4 = 0; k4 < 32; ++k4) {         // 4 k's per iter
            float4 a[4];                           // 4 rows x 4 k's
            #pragma unroll
            for (int rr = 0; rr < 4; ++rr)
                a[rr] = *reinterpret_cast<const float4*>(&As[ty * 4 + rr][k4 * 4]);
            float4 w[4];                           // 4 k's x 4 cols
            #pragma unroll
            for (int kk = 0; kk < 4; ++kk)
                w[kk] = *reinterpret_cast<const float4*>(&Ws[k4 * 4 + kk][tx * 4]);
            #pragma unroll
            for (int rr = 0; rr < 4; ++rr) {
                const float* ar = reinterpret_cast<const float*>(&a[rr]);
                #pragma unroll
                for (int kk = 0; kk < 4; ++kk) {
                    acc[rr][0] = fmaf(ar[kk], w[kk].x, acc[rr][0]);
                    acc[rr][1] = fmaf(ar[kk], w[kk].y, acc[rr][1]);
                    acc[rr][2] = fmaf(ar[kk], w[kk].z, acc[rr][2]);
                    acc[rr][3] = fmaf(ar[kk], w[kk].w, acc[rr][3]);
                }
            }
        }

        // Epilogue for this col-half: bias + relu + in-place store (own rows only)
        const float4 bb = *reinterpret_cast<const float4*>(&bias[h * 64 + tx * 4]);
        #pragma unroll
        for (int rr = 0; rr < 4; ++rr) {
            const int r = ty * 4 + rr;
            if (r < rows_here) {
                float4 o;
                o.x = fmaxf(acc[rr][0] + bb.x, 0.f);
                o.y = fmaxf(acc[rr][1] + bb.y, 0.f);
                o.z = fmaxf(acc[rr][2] + bb.z, 0.f);
                o.w = fmaxf(acc[rr][3] + bb.w, 0.f);
                *reinterpret_cast<float4*>(
                    &out[(size_t)(r0 + r) * F_OUT + h * 64 + tx * 4]) = o;
            }
        }
    }
}

extern "C" void kernel_launch(void* const* d_in, const int* in_sizes, int n_in,
                              void* d_out, int out_size, void* d_ws, size_t ws_size,
                              hipStream_t stream) {
    const float* x    = (const float*)d_in[0];
    const int*   rows = (const int*)  d_in[1];
    const int*   cols = (const int*)  d_in[2];
    const float* vals = (const float*)d_in[3];
    const float* W    = (const float*)d_in[4];
    const float* b    = (const float*)d_in[5];
    float* out = (float*)d_out;

    const bool use_rowptr = ws_size >= (size_t)(N_NODES + 1) * sizeof(int);

    if (use_rowptr) {
        int* rowptr = (int*)d_ws;
        build_rowptr_kernel<<<(N_NODES + 256) / 256, 256, 0, stream>>>(rows, rowptr);
        spmm_ax_kernel<true><<<(N_NODES + 3) / 4, 256, 0, stream>>>(
            x, rows, cols, vals, rowptr, out);
    } else {
        spmm_ax_kernel<false><<<(N_NODES + 3) / 4, 256, 0, stream>>>(
            x, rows, cols, vals, nullptr, out);
    }
    gemm_bias_relu_inplace<<<(N_NODES + 63) / 64, 256, 0, stream>>>(out, W, b);
}

// Round 4
// 373.923 us; speedup vs baseline: 1.5766x; 1.0563x over previous
//
#include <hip/hip_runtime.h>
#include <cstdint>
#include <cstddef>

#define N_NODES 100000
#define N_EDGES 3200000
#define F_IN 128
#define F_OUT 128
#define KPAD 136

#define ROWPTR_BYTES ((N_NODES + 1) * 4)
#define WT_OFF ((ROWPTR_BYTES + 255) & ~255)          // 256-aligned
#define WT_BYTES (F_OUT * KPAD * 2)                   // bf16 Wt[128][136]
#define WS_NEED (WT_OFF + WT_BYTES)

typedef __attribute__((ext_vector_type(8))) short short8;   // 8 bf16 (4 VGPRs)
typedef __attribute__((ext_vector_type(4))) float f32x4;    // MFMA accumulator

// f32 -> bf16, round-to-nearest-even
__device__ __forceinline__ unsigned short f2bf(float f) {
    union { float f; unsigned u; } v; v.f = f;
    return (unsigned short)((v.u + 0x7FFFu + ((v.u >> 16) & 1u)) >> 16);
}

__device__ __forceinline__ int lower_bound_i32(const int* __restrict__ a, int n, int key) {
    int lo = 0, hi = n;
    while (lo < hi) {
        int mid = (lo + hi) >> 1;
        if (a[mid] < key) lo = mid + 1; else hi = mid;
    }
    return lo;
}

// rowptr[n] = first edge index with rows[e] >= n
__global__ __launch_bounds__(256) void build_rowptr_kernel(
    const int* __restrict__ rows, int* __restrict__ rowptr)
{
    const int n = blockIdx.x * 256 + threadIdx.x;
    if (n <= N_NODES) rowptr[n] = lower_bound_i32(rows, N_EDGES, n);
}

// Wt[c][k] = bf16(W[k][c]), rows padded to KPAD
__global__ __launch_bounds__(256) void build_wt_kernel(
    const float* __restrict__ W, unsigned short* __restrict__ Wt)
{
    const int idx = blockIdx.x * 256 + threadIdx.x;   // c*128 + k
    if (idx < F_IN * F_OUT) {
        const int c = idx >> 7, k = idx & 127;
        Wt[c * KPAD + k] = f2bf(W[k * F_OUT + c]);
    }
}

// out[row,:] = sum_e vals[e] * x[cols[e],:] — one wave/row, lane owns float2, 8-deep MLP.
template<bool USE_ROWPTR>
__global__ __launch_bounds__(256) void spmm_ax_kernel(
    const float* __restrict__ x,
    const int*   __restrict__ rows,
    const int*   __restrict__ cols,
    const float* __restrict__ vals,
    const int*   __restrict__ rowptr,
    float*       __restrict__ out)
{
    const int row  = blockIdx.x * 4 + (threadIdx.x >> 6);
    const int lane = threadIdx.x & 63;
    if (row >= N_NODES) return;

    int e0, e1;
    if (USE_ROWPTR) { e0 = rowptr[row]; e1 = rowptr[row + 1]; }
    else {
        e0 = lower_bound_i32(rows, N_EDGES, row);
        e1 = lower_bound_i32(rows, N_EDGES, row + 1);
    }

    const float2* __restrict__ x2 = reinterpret_cast<const float2*>(x);
    float ax = 0.f, ay = 0.f;

    int e = e0;
    for (; e + 8 <= e1; e += 8) {
        int c[8]; float v[8]; float2 a[8];
        #pragma unroll
        for (int j = 0; j < 8; ++j) { c[j] = cols[e + j]; v[j] = vals[e + j]; }
        #pragma unroll
        for (int j = 0; j < 8; ++j) a[j] = x2[(unsigned)c[j] * 64u + lane];
        #pragma unroll
        for (int j = 0; j < 8; ++j) {
            ax = fmaf(v[j], a[j].x, ax);
            ay = fmaf(v[j], a[j].y, ay);
        }
    }
    for (; e < e1; ++e) {
        const int   c = cols[e];
        const float v = vals[e];
        const float2 a = x2[(unsigned)c * 64u + lane];
        ax = fmaf(v, a.x, ax); ay = fmaf(v, a.y, ay);
    }

    float2 o; o.x = ax; o.y = ay;
    reinterpret_cast<float2*>(out)[(size_t)row * 64 + lane] = o;
}

// In-place out[r,:] = relu(bf16(out[r,:]) @ bf16(W) + b) via mfma_f32_16x16x32_bf16.
// Block = 64 rows x 128 cols; 4 waves x (16 rows x 8 col-tiles); K=128 in 4 steps.
// Fragments: lane&15 = A-row / B-col, (lane>>4)*8 = k-chunk (contiguous short8 b128 loads).
// C/D: col = lane&15, row = (lane>>4)*4 + reg  [verified layout].
// In-place safe: block stages its own 64 rows into LDS before any store; rows disjoint.
template<bool WT_WS>
__global__ __launch_bounds__(256) void gemm_mfma_bias_relu_inplace(
    float*                __restrict__ out,
    const unsigned short* __restrict__ Wt_ws,   // bf16 Wt[128][KPAD] (if WT_WS)
    const float*          __restrict__ W,       // raw W (fallback transpose)
    const float*          __restrict__ bias)
{
    __shared__ short A_lds[64][KPAD];     // 17408 B
    __shared__ short Wt_lds[F_OUT][KPAD]; // 34816 B  -> total 52224 B, 3 blocks/CU

    const int t  = threadIdx.x;
    const int r0 = blockIdx.x * 64;
    const int rows_here = (N_NODES - r0 < 64) ? (N_NODES - r0) : 64;

    // Stage A rows (f32 -> bf16) into LDS
    {
        const float4* __restrict__ A4 =
            reinterpret_cast<const float4*>(out + (size_t)r0 * F_IN);
        const int nA = rows_here * 32;                 // 32 float4 per row
        for (int i = t; i < nA; i += 256) {
            const int r = i >> 5, q = i & 31;
            const float4 va = A4[i];
            uint2 p;
            p.x = (unsigned)f2bf(va.x) | ((unsigned)f2bf(va.y) << 16);
            p.y = (unsigned)f2bf(va.z) | ((unsigned)f2bf(va.w) << 16);
            *reinterpret_cast<uint2*>(&A_lds[r][q * 4]) = p;   // 8B aligned
        }
    }

    // Stage Wt into LDS
    if (WT_WS) {
        const float4* __restrict__ src = reinterpret_cast<const float4*>(Wt_ws);
        float4* dst = reinterpret_cast<float4*>(&Wt_lds[0][0]);
        for (int i = t; i < (WT_BYTES / 16); i += 256) dst[i] = src[i];
    } else {
        if (t < F_OUT) {
            for (int k = 0; k < F_IN; ++k)
                Wt_lds[t][k] = (short)f2bf(W[k * F_OUT + t]);
        }
    }
    __syncthreads();

    const int lane = t & 63;
    const int w    = t >> 6;        // wave id 0..3 -> rows w*16..w*16+15
    const int lr   = lane & 15;     // A-row / B-col within tile
    const int lg   = lane >> 4;     // k-chunk group

    f32x4 acc[8];
    #pragma unroll
    for (int n = 0; n < 8; ++n) acc[n] = (f32x4){0.f, 0.f, 0.f, 0.f};

    #pragma unroll
    for (int ks = 0; ks < 4; ++ks) {
        const short8 a = *reinterpret_cast<const short8*>(
            &A_lds[w * 16 + lr][ks * 32 + lg * 8]);
        #pragma unroll
        for (int n = 0; n < 8; ++n) {
            const short8 b = *reinterpret_cast<const short8*>(
                &Wt_lds[n * 16 + lr][ks * 32 + lg * 8]);
            acc[n] = __builtin_amdgcn_mfma_f32_16x16x32_bf16(a, b, acc[n], 0, 0, 0);
        }
    }

    // Epilogue: bias + relu, in-place store (own rows only)
    const int row_base = r0 + w * 16 + lg * 4;
    #pragma unroll
    for (int n = 0; n < 8; ++n) {
        const int col = n * 16 + lr;
        const float bb = bias[col];
        #pragma unroll
        for (int reg = 0; reg < 4; ++reg) {
            const int r = row_base + reg;
            if (r < N_NODES)
                out[(size_t)r * F_OUT + col] = fmaxf(acc[n][reg] + bb, 0.f);
        }
    }
}

extern "C" void kernel_launch(void* const* d_in, const int* in_sizes, int n_in,
                              void* d_out, int out_size, void* d_ws, size_t ws_size,
                              hipStream_t stream) {
    const float* x    = (const float*)d_in[0];
    const int*   rows = (const int*)  d_in[1];
    const int*   cols = (const int*)  d_in[2];
    const float* vals = (const float*)d_in[3];
    const float* W    = (const float*)d_in[4];
    const float* b    = (const float*)d_in[5];
    float* out = (float*)d_out;

    const bool ws_ok = ws_size >= (size_t)WS_NEED;

    if (ws_ok) {
        int* rowptr = (int*)d_ws;
        unsigned short* Wt = (unsigned short*)((char*)d_ws + WT_OFF);
        build_rowptr_kernel<<<(N_NODES + 256) / 256, 256, 0, stream>>>(rows, rowptr);
        build_wt_kernel<<<(F_IN * F_OUT + 255) / 256, 256, 0, stream>>>(W, Wt);
        spmm_ax_kernel<true><<<(N_NODES + 3) / 4, 256, 0, stream>>>(
            x, rows, cols, vals, rowptr, out);
        gemm_mfma_bias_relu_inplace<true><<<(N_NODES + 63) / 64, 256, 0, stream>>>(
            out, Wt, W, b);
    } else {
        spmm_ax_kernel<false><<<(N_NODES + 3) / 4, 256, 0, stream>>>(
            x, rows, cols, vals, nullptr, out);
        gemm_mfma_bias_relu_inplace<false><<<(N_NODES + 63) / 64, 256, 0, stream>>>(
            out, nullptr, W, b);
    }
}

// Round 5
// 274.767 us; speedup vs baseline: 2.1456x; 1.3609x over previous
//
#include <hip/hip_runtime.h>
#include <cstdint>
#include <cstddef>

#define N_NODES 100000
#define N_EDGES 3200000
#define F_IN 128
#define F_OUT 128
#define KPAD 136   // Tier-B fallback gemm only

// ---------------- workspace layout ----------------
#define ROWPTR_BYTES ((N_NODES + 1) * 4)
#define O_XB   (((ROWPTR_BYTES) + 255) & ~255)        // 400,128
#define XB_BYTES (N_NODES * F_IN * 2)                 // 25,600,000
#define O_AXB  (O_XB + XB_BYTES)                      // 26,000,128
#define AXB_BYTES (N_NODES * F_OUT * 2)               // 25,600,000
#define O_WT_A (O_AXB + AXB_BYTES)                    // 51,600,128
#define WT_SWZ_BYTES (F_OUT * F_IN * 2)               // 32,768
#define NEED_A ((size_t)(O_WT_A + WT_SWZ_BYTES))      // 51,632,896
#define O_WT_A2 O_AXB
#define WT_KPAD_BYTES (F_OUT * KPAD * 2)
#define NEED_A2 ((size_t)(O_WT_A2 + WT_KPAD_BYTES))
#define O_WT_B O_XB
#define NEED_B ((size_t)(O_WT_B + WT_KPAD_BYTES))

typedef __attribute__((ext_vector_type(8))) short short8;   // 8 bf16
typedef __attribute__((ext_vector_type(4))) float f32x4;

// f32 -> bf16 round-to-nearest-even
__device__ __forceinline__ unsigned short f2bf(float f) {
    union { float f; unsigned u; } v; v.f = f;
    return (unsigned short)((v.u + 0x7FFFu + ((v.u >> 16) & 1u)) >> 16);
}
__device__ __forceinline__ float bflo(unsigned u) {  // low bf16 of packed uint
    union { unsigned u; float f; } v; v.u = u << 16; return v.f;
}
__device__ __forceinline__ float bfhi(unsigned u) {  // high bf16 of packed uint
    union { unsigned u; float f; } v; v.u = u & 0xFFFF0000u; return v.f;
}

__device__ __forceinline__ int lower_bound_i32(const int* __restrict__ a, int n, int key) {
    int lo = 0, hi = n;
    while (lo < hi) {
        int mid = (lo + hi) >> 1;
        if (a[mid] < key) lo = mid + 1; else hi = mid;
    }
    return lo;
}

__global__ __launch_bounds__(256) void build_rowptr_kernel(
    const int* __restrict__ rows, int* __restrict__ rowptr)
{
    const int n = blockIdx.x * 256 + threadIdx.x;
    if (n <= N_NODES) rowptr[n] = lower_bound_i32(rows, N_EDGES, n);
}

// x f32 -> xb bf16 (linear layout), 8 elems/thread
__global__ __launch_bounds__(256) void convert_x_kernel(
    const float4* __restrict__ x4, unsigned short* __restrict__ xb)
{
    const unsigned i = blockIdx.x * 256 + threadIdx.x;       // over 1.6M
    if (i < (N_NODES * F_IN / 8)) {
        const float4 a = x4[2 * i], b = x4[2 * i + 1];
        uint4 p;
        p.x = (unsigned)f2bf(a.x) | ((unsigned)f2bf(a.y) << 16);
        p.y = (unsigned)f2bf(a.z) | ((unsigned)f2bf(a.w) << 16);
        p.z = (unsigned)f2bf(b.x) | ((unsigned)f2bf(b.y) << 16);
        p.w = (unsigned)f2bf(b.z) | ((unsigned)f2bf(b.w) << 16);
        *reinterpret_cast<uint4*>(xb + (size_t)i * 8) = p;
    }
}

// Wt (bf16, XOR-swizzled rows of 256B): element k of col c at byte c*256 + ((2k)^((c&7)<<4))
__global__ __launch_bounds__(256) void build_wt_swz_kernel(
    const float* __restrict__ W, char* __restrict__ Wt)
{
    const int idx = blockIdx.x * 256 + threadIdx.x;          // c*128 + k
    if (idx < F_IN * F_OUT) {
        const int c = idx >> 7, k = idx & 127;
        *reinterpret_cast<unsigned short*>(
            Wt + c * 256 + ((k * 2) ^ ((c & 7) << 4))) = f2bf(W[k * F_OUT + c]);
    }
}

// Tier-B Wt: bf16 Wt[c][k], rows padded to KPAD
__global__ __launch_bounds__(256) void build_wt_kpad_kernel(
    const float* __restrict__ W, unsigned short* __restrict__ Wt)
{
    const int idx = blockIdx.x * 256 + threadIdx.x;
    if (idx < F_IN * F_OUT) {
        const int c = idx >> 7, k = idx & 127;
        Wt[c * KPAD + k] = f2bf(W[k * F_OUT + c]);
    }
}

// SpMM over bf16 x: one wave/row, lane owns 2 features, 8-deep gather unroll.
// OUT_MODE 0: f32 float2 -> d_out ; OUT_MODE 1: packed bf16, XOR-swizzled -> AXb(ws)
template<int OUT_MODE>
__global__ __launch_bounds__(256) void spmm_xb_kernel(
    const unsigned* __restrict__ xb,     // [node][64] packed bf16 pairs
    const int*      __restrict__ cols,
    const float*    __restrict__ vals,
    const int*      __restrict__ rowptr,
    void*           __restrict__ outp)
{
    const int row  = blockIdx.x * 4 + (threadIdx.x >> 6);
    const int lane = threadIdx.x & 63;
    if (row >= N_NODES) return;

    const int e0 = rowptr[row], e1 = rowptr[row + 1];
    float ax = 0.f, ay = 0.f;

    int e = e0;
    for (; e + 8 <= e1; e += 8) {
        int c[8]; float v[8]; unsigned u[8];
        #pragma unroll
        for (int j = 0; j < 8; ++j) { c[j] = cols[e + j]; v[j] = vals[e + j]; }
        #pragma unroll
        for (int j = 0; j < 8; ++j) u[j] = xb[(unsigned)c[j] * 64u + lane];
        #pragma unroll
        for (int j = 0; j < 8; ++j) {
            ax = fmaf(v[j], bflo(u[j]), ax);
            ay = fmaf(v[j], bfhi(u[j]), ay);
        }
    }
    for (; e < e1; ++e) {
        const float v = vals[e];
        const unsigned u = xb[(unsigned)cols[e] * 64u + lane];
        ax = fmaf(v, bflo(u), ax);
        ay = fmaf(v, bfhi(u), ay);
    }

    if (OUT_MODE == 0) {
        float2 o; o.x = ax; o.y = ay;
        reinterpret_cast<float2*>(outp)[(size_t)row * 64 + lane] = o;
    } else {
        const unsigned p = (unsigned)f2bf(ax) | ((unsigned)f2bf(ay) << 16);
        *reinterpret_cast<unsigned*>(
            (char*)outp + (size_t)row * 256 + ((lane * 4) ^ ((row & 7) << 4))) = p;
    }
}

// GEMM: out[r,:] = relu(AXb[r,:] @ W + b). AXb/Wt are bf16, rows 256B, XOR-swizzled.
// Stage both linearly into LDS; fragment reads apply the same swizzle -> bank-uniform.
// Block = 64 rows x 128 cols, 4 waves x (16 rows x 8 col-tiles), mfma_f32_16x16x32_bf16.
__global__ __launch_bounds__(256) void gemm_ws_mfma(
    const char*  __restrict__ AXb,
    const char*  __restrict__ Wt,
    const float* __restrict__ bias,
    float*       __restrict__ out)
{
    __shared__ uint4 A_lds4[64 * 16];    // 16 KB
    __shared__ uint4 W_lds4[128 * 16];   // 32 KB  -> 48 KB total, 3 blocks/CU
    const int t  = threadIdx.x;
    const int r0 = blockIdx.x * 64;

    // Linear stage (source already swizzled by producers). Last block over-reads
    // 8 KB past AXb into the adjacent Wt region (allocated) — rows guarded at store.
    {
        const uint4* As = reinterpret_cast<const uint4*>(AXb + (size_t)blockIdx.x * 16384);
        #pragma unroll
        for (int i = 0; i < 4; ++i) A_lds4[t + 256 * i] = As[t + 256 * i];
        const uint4* Ws = reinterpret_cast<const uint4*>(Wt);
        #pragma unroll
        for (int i = 0; i < 8; ++i) W_lds4[t + 256 * i] = Ws[t + 256 * i];
    }
    __syncthreads();

    const char* A_lds = reinterpret_cast<const char*>(A_lds4);
    const char* W_lds = reinterpret_cast<const char*>(W_lds4);

    const int lane = t & 63;
    const int w    = t >> 6;
    const int lr   = lane & 15;
    const int lg   = lane >> 4;
    const int sw   = (lr & 7) << 4;      // swizzle term: rows/cols ≡ lr (mod 8)

    f32x4 acc[8];
    #pragma unroll
    for (int n = 0; n < 8; ++n) acc[n] = (f32x4){0.f, 0.f, 0.f, 0.f};

    const char* Abase = A_lds + (w * 16 + lr) * 256;
    #pragma unroll
    for (int ks = 0; ks < 4; ++ks) {
        const int koff = (ks * 64 + lg * 16) ^ sw;
        const short8 a = *reinterpret_cast<const short8*>(Abase + koff);
        #pragma unroll
        for (int n = 0; n < 8; ++n) {
            const short8 b = *reinterpret_cast<const short8*>(
                W_lds + (n * 16 + lr) * 256 + koff);
            acc[n] = __builtin_amdgcn_mfma_f32_16x16x32_bf16(a, b, acc[n], 0, 0, 0);
        }
    }

    // C/D: col = n*16 + (lane&15), row = w*16 + (lane>>4)*4 + reg  [verified r4]
    const int row_base = r0 + w * 16 + lg * 4;
    #pragma unroll
    for (int n = 0; n < 8; ++n) {
        const int col = n * 16 + lr;
        const float bb = bias[col];
        #pragma unroll
        for (int reg = 0; reg < 4; ++reg) {
            const int r = row_base + reg;
            if (r < N_NODES)
                out[(size_t)r * F_OUT + col] = fmaxf(acc[n][reg] + bb, 0.f);
        }
    }
}

// ---------------- Tier-B fallback kernels (round-4, known-good) ----------------
template<bool USE_ROWPTR>
__global__ __launch_bounds__(256) void spmm_ax_kernel(
    const float* __restrict__ x,
    const int*   __restrict__ rows,
    const int*   __restrict__ cols,
    const float* __restrict__ vals,
    const int*   __restrict__ rowptr,
    float*       __restrict__ out)
{
    const int row  = blockIdx.x * 4 + (threadIdx.x >> 6);
    const int lane = threadIdx.x & 63;
    if (row >= N_NODES) return;

    int e0, e1;
    if (USE_ROWPTR) { e0 = rowptr[row]; e1 = rowptr[row + 1]; }
    else {
        e0 = lower_bound_i32(rows, N_EDGES, row);
        e1 = lower_bound_i32(rows, N_EDGES, row + 1);
    }
    const float2* __restrict__ x2 = reinterpret_cast<const float2*>(x);
    float ax = 0.f, ay = 0.f;
    int e = e0;
    for (; e + 8 <= e1; e += 8) {
        int c[8]; float v[8]; float2 a[8];
        #pragma unroll
        for (int j = 0; j < 8; ++j) { c[j] = cols[e + j]; v[j] = vals[e + j]; }
        #pragma unroll
        for (int j = 0; j < 8; ++j) a[j] = x2[(unsigned)c[j] * 64u + lane];
        #pragma unroll
        for (int j = 0; j < 8; ++j) {
            ax = fmaf(v[j], a[j].x, ax); ay = fmaf(v[j], a[j].y, ay);
        }
    }
    for (; e < e1; ++e) {
        const float v = vals[e];
        const float2 a = x2[(unsigned)cols[e] * 64u + lane];
        ax = fmaf(v, a.x, ax); ay = fmaf(v, a.y, ay);
    }
    float2 o; o.x = ax; o.y = ay;
    reinterpret_cast<float2*>(out)[(size_t)row * 64 + lane] = o;
}

template<bool WT_WS>
__global__ __launch_bounds__(256) void gemm_mfma_bias_relu_inplace(
    float*                __restrict__ out,
    const unsigned short* __restrict__ Wt_ws,
    const float*          __restrict__ W,
    const float*          __restrict__ bias)
{
    __shared__ short A_lds[64][KPAD];
    __shared__ short Wt_lds[F_OUT][KPAD];
    const int t  = threadIdx.x;
    const int r0 = blockIdx.x * 64;
    const int rows_here = (N_NODES - r0 < 64) ? (N_NODES - r0) : 64;
    {
        const float4* __restrict__ A4 =
            reinterpret_cast<const float4*>(out + (size_t)r0 * F_IN);
        const int nA = rows_here * 32;
        for (int i = t; i < nA; i += 256) {
            const int r = i >> 5, q = i & 31;
            const float4 va = A4[i];
            uint2 p;
            p.x = (unsigned)f2bf(va.x) | ((unsigned)f2bf(va.y) << 16);
            p.y = (unsigned)f2bf(va.z) | ((unsigned)f2bf(va.w) << 16);
            *reinterpret_cast<uint2*>(&A_lds[r][q * 4]) = p;
        }
    }
    if (WT_WS) {
        const float4* __restrict__ src = reinterpret_cast<const float4*>(Wt_ws);
        float4* dst = reinterpret_cast<float4*>(&Wt_lds[0][0]);
        for (int i = t; i < (WT_KPAD_BYTES / 16); i += 256) dst[i] = src[i];
    } else {
        if (t < F_OUT)
            for (int k = 0; k < F_IN; ++k)
                Wt_lds[t][k] = (short)f2bf(W[k * F_OUT + t]);
    }
    __syncthreads();

    const int lane = t & 63, w = t >> 6, lr = lane & 15, lg = lane >> 4;
    f32x4 acc[8];
    #pragma unroll
    for (int n = 0; n < 8; ++n) acc[n] = (f32x4){0.f, 0.f, 0.f, 0.f};
    #pragma unroll
    for (int ks = 0; ks < 4; ++ks) {
        const short8 a = *reinterpret_cast<const short8*>(
            &A_lds[w * 16 + lr][ks * 32 + lg * 8]);
        #pragma unroll
        for (int n = 0; n < 8; ++n) {
            const short8 b = *reinterpret_cast<const short8*>(
                &Wt_lds[n * 16 + lr][ks * 32 + lg * 8]);
            acc[n] = __builtin_amdgcn_mfma_f32_16x16x32_bf16(a, b, acc[n], 0, 0, 0);
        }
    }
    const int row_base = r0 + w * 16 + lg * 4;
    #pragma unroll
    for (int n = 0; n < 8; ++n) {
        const int col = n * 16 + lr;
        const float bb = bias[col];
        #pragma unroll
        for (int reg = 0; reg < 4; ++reg) {
            const int r = row_base + reg;
            if (r < N_NODES)
                out[(size_t)r * F_OUT + col] = fmaxf(acc[n][reg] + bb, 0.f);
        }
    }
}

extern "C" void kernel_launch(void* const* d_in, const int* in_sizes, int n_in,
                              void* d_out, int out_size, void* d_ws, size_t ws_size,
                              hipStream_t stream) {
    const float* x    = (const float*)d_in[0];
    const int*   rows = (const int*)  d_in[1];
    const int*   cols = (const int*)  d_in[2];
    const float* vals = (const float*)d_in[3];
    const float* W    = (const float*)d_in[4];
    const float* b    = (const float*)d_in[5];
    float* out = (float*)d_out;
    char*  ws  = (char*)d_ws;

    if (ws_size >= NEED_A) {
        int* rowptr = (int*)ws;
        unsigned short* xb = (unsigned short*)(ws + O_XB);
        char* AXb = ws + O_AXB;
        char* Wt  = ws + O_WT_A;
        build_rowptr_kernel<<<(N_NODES + 256) / 256, 256, 0, stream>>>(rows, rowptr);
        convert_x_kernel<<<(N_NODES * F_IN / 8 + 255) / 256, 256, 0, stream>>>(
            (const float4*)x, xb);
        build_wt_swz_kernel<<<(F_IN * F_OUT + 255) / 256, 256, 0, stream>>>(W, Wt);
        spmm_xb_kernel<1><<<(N_NODES + 3) / 4, 256, 0, stream>>>(
            (const unsigned*)xb, cols, vals, rowptr, AXb);
        gemm_ws_mfma<<<(N_NODES + 63) / 64, 256, 0, stream>>>(AXb, Wt, b, out);
    } else if (ws_size >= NEED_A2) {
        int* rowptr = (int*)ws;
        unsigned short* xb = (unsigned short*)(ws + O_XB);
        unsigned short* Wt = (unsigned short*)(ws + O_WT_A2);
        build_rowptr_kernel<<<(N_NODES + 256) / 256, 256, 0, stream>>>(rows, rowptr);
        convert_x_kernel<<<(N_NODES * F_IN / 8 + 255) / 256, 256, 0, stream>>>(
            (const float4*)x, xb);
        build_wt_kpad_kernel<<<(F_IN * F_OUT + 255) / 256, 256, 0, stream>>>(W, Wt);
        spmm_xb_kernel<0><<<(N_NODES + 3) / 4, 256, 0, stream>>>(
            (const unsigned*)xb, cols, vals, rowptr, out);
        gemm_mfma_bias_relu_inplace<true><<<(N_NODES + 63) / 64, 256, 0, stream>>>(
            out, Wt, nullptr, b);
    } else if (ws_size >= NEED_B) {
        int* rowptr = (int*)ws;
        unsigned short* Wt = (unsigned short*)(ws + O_WT_B);
        build_rowptr_kernel<<<(N_NODES + 256) / 256, 256, 0, stream>>>(rows, rowptr);
        build_wt_kpad_kernel<<<(F_IN * F_OUT + 255) / 256, 256, 0, stream>>>(W, Wt);
        spmm_ax_kernel<true><<<(N_NODES + 3) / 4, 256, 0, stream>>>(
            x, rows, cols, vals, rowptr, out);
        gemm_mfma_bias_relu_inplace<true><<<(N_NODES + 63) / 64, 256, 0, stream>>>(
            out, Wt, nullptr, b);
    } else {
        spmm_ax_kernel<false><<<(N_NODES + 3) / 4, 256, 0, stream>>>(
            x, rows, cols, vals, nullptr, out);
        gemm_mfma_bias_relu_inplace<false><<<(N_NODES + 63) / 64, 256, 0, stream>>>(
            out, nullptr, W, b);
    }
}